// Round 1
// baseline (572.000 us; speedup 1.0000x reference)
//
#include <hip/hip_runtime.h>

// Problem constants (fixed by reference setup_inputs)
constexpr int B  = 4;
constexpr int C  = 128;    // == Cv
constexpr int hw = 16384;  // h*w = 128*128
constexpr int W_ = 256;
constexpr int HW = 65536;  // H*W
constexpr int K  = 16;
constexpr int P_TILE = 16;                       // positions per block
constexpr int BLOCKS_PER_BATCH = hw / P_TILE;    // 1024

// (C, N) fp32 -> (N, C) fp32, one batch per blockIdx.z  (per-batch fallback path)
__global__ __launch_bounds__(256) void transpose_f32(
    const float* __restrict__ src, float* __restrict__ dst, int N)
{
    __shared__ float tile[64][65];
    const int bz = blockIdx.z;
    const int n0 = blockIdx.x * 64;
    const int c0 = blockIdx.y * 64;
    const int tx = threadIdx.x;   // 0..63
    const int ty = threadIdx.y;   // 0..3
    const float* s = src + (size_t)bz * C * N;
    float* d = dst + (size_t)bz * N * C;
    #pragma unroll
    for (int i = 0; i < 16; ++i) {
        int cl = ty + i * 4;
        tile[cl][tx] = s[(size_t)(c0 + cl) * N + n0 + tx];   // coalesced 256B
    }
    __syncthreads();
    #pragma unroll
    for (int i = 0; i < 16; ++i) {
        int nl = ty + i * 4;
        d[(size_t)(n0 + nl) * C + c0 + tx] = tile[tx][nl];   // coalesced 256B
    }
}

// Fused transpose of both S and R (all batches) in one launch.
// blockIdx.z in [0, 2B): z<B -> S batch z, else R batch z-B.
__global__ __launch_bounds__(256) void transpose_f32_both(
    const float* __restrict__ S, const float* __restrict__ R,
    float* __restrict__ St, float* __restrict__ Rt)
{
    __shared__ float tile[64][65];
    const int z  = blockIdx.z;
    const float* src = (z < B) ? (S + (size_t)z * C * HW)
                               : (R + (size_t)(z - B) * C * HW);
    float* dst       = (z < B) ? (St + (size_t)z * HW * C)
                               : (Rt + (size_t)(z - B) * HW * C);
    const int n0 = blockIdx.x * 64;
    const int c0 = blockIdx.y * 64;
    const int tx = threadIdx.x;   // 0..63
    const int ty = threadIdx.y;   // 0..3
    #pragma unroll
    for (int i = 0; i < 16; ++i) {
        int cl = ty + i * 4;
        tile[cl][tx] = src[(size_t)(c0 + cl) * HW + n0 + tx];   // coalesced 256B
    }
    __syncthreads();
    #pragma unroll
    for (int i = 0; i < 16; ++i) {
        int nl = ty + i * 4;
        dst[(size_t)(n0 + nl) * C + c0 + tx] = tile[tx][nl];    // coalesced 256B
    }
}

// Gather-attention from transposed fp32 K/V (exact math vs reference).
// St/Rt hold batches [b0 .. b0 + gridBatches) contiguously.
// Phase 1 and phase 2 both use the same access pattern: 16 lanes span one
// contiguous 512B row -> fully-utilized cache lines, ~8x fewer TCC requests
// than the per-lane-sequential walk.
__global__ __launch_bounds__(256) void attn_gather(
    const float* __restrict__ Q, const int* __restrict__ Pos,
    const float* __restrict__ St, const float* __restrict__ Rt,
    float* __restrict__ outBuf, float* __restrict__ outM, int b0)
{
    __shared__ float q_s[P_TILE][132];   // Q tile, fp32, padded (conflict-free float4)
    __shared__ float attn_s[P_TILE][17];
    __shared__ int   idx_s[P_TILE][K];
    __shared__ float out_s[P_TILE][132];

    const int tid = threadIdx.x;
    const int bb  = blockIdx.x / BLOCKS_PER_BATCH;   // batch within this launch
    const int b   = b0 + bb;                         // absolute batch
    const int p0  = (blockIdx.x % BLOCKS_PER_BATCH) * P_TILE;

    // ---- phase 0: stage Q tile (coalesced) + compute gather indices ----
    for (int i = tid; i < P_TILE * C; i += 256) {
        int c = i >> 4, pl0 = i & 15;
        q_s[pl0][c] = Q[((size_t)(b * C + c)) * hw + p0 + pl0];
    }
    const int pl = tid >> 4;   // position in tile (= 16-lane group id)
    const int cg = tid & 15;   // lane within group (channel chunk / k index)
    const int p  = p0 + pl;
    {
        const int rr = Pos[(((size_t)(b * 2 + 0) * hw) + p) * K + cg];
        const int cc = Pos[(((size_t)(b * 2 + 1) * hw) + p) * K + cg];
        idx_s[pl][cg] = rr * W_ + cc;
    }
    __syncthreads();

    // ---- phase 1: score[k] = q . K_row[idx[k]], cooperatively per 16-lane group.
    // Lane cg holds q[cg*8 .. cg*8+7] in registers; per k-row the group loads
    // 512B contiguous (2 float4/lane), partial-dots, butterfly-reduces; lane
    // cg==k keeps the score. ----
    float qf[8];
    #pragma unroll
    for (int i = 0; i < 8; ++i) qf[i] = q_s[pl][cg * 8 + i];

    float score = 0.f;
    #pragma unroll
    for (int k2 = 0; k2 < K; ++k2) {
        const float4* srow = reinterpret_cast<const float4*>(
            St + ((size_t)bb * HW + idx_s[pl][k2]) * C);   // idx_s broadcast (same addr per group)
        float4 s0 = srow[cg * 2];                          // 512B contiguous per 16 lanes
        float4 s1 = srow[cg * 2 + 1];
        float part = qf[0] * s0.x + qf[1] * s0.y + qf[2] * s0.z + qf[3] * s0.w
                   + qf[4] * s1.x + qf[5] * s1.y + qf[6] * s1.z + qf[7] * s1.w;
        #pragma unroll
        for (int off = 1; off < 16; off <<= 1) part += __shfl_xor(part, off);
        if (cg == k2) score = part;                        // cndmask, no divergence cost
    }

    // softmax over k (lane cg holds score for k=cg)
    float mx = score;
    #pragma unroll
    for (int off = 1; off < 16; off <<= 1) mx = fmaxf(mx, __shfl_xor(mx, off));
    float e = __expf(score - mx);
    float ssum = e;
    #pragma unroll
    for (int off = 1; off < 16; off <<= 1) ssum += __shfl_xor(ssum, off);
    const float attn = e / ssum;
    outM[((size_t)b * hw + p) * K + cg] = attn;   // coalesced
    attn_s[pl][cg] = attn;
    __syncthreads();

    // ---- phase 2: out[c] = sum_k attn * V_row[c]; 16 lanes span one 512B V row ----
    {
        float acc[8];
        #pragma unroll
        for (int i = 0; i < 8; ++i) acc[i] = 0.f;
        #pragma unroll
        for (int k2 = 0; k2 < K; ++k2) {
            const float a = attn_s[pl][k2];
            const float4* rrow = reinterpret_cast<const float4*>(
                Rt + ((size_t)bb * HW + idx_s[pl][k2]) * C);
            float4 r0 = rrow[cg * 2];                             // 512B contiguous per 16 lanes
            float4 r1 = rrow[cg * 2 + 1];
            acc[0] += a * r0.x; acc[1] += a * r0.y;
            acc[2] += a * r0.z; acc[3] += a * r0.w;
            acc[4] += a * r1.x; acc[5] += a * r1.y;
            acc[6] += a * r1.z; acc[7] += a * r1.w;
        }
        #pragma unroll
        for (int i = 0; i < 8; ++i) out_s[pl][cg * 8 + i] = acc[i];
    }
    __syncthreads();
    for (int i = tid; i < P_TILE * C; i += 256) {
        int c = i >> 4, pl3 = i & 15;
        outBuf[((size_t)(b * C + c)) * hw + p0 + pl3] = out_s[pl3][c];   // coalesced
    }
}

// Fallback: direct gather from original (B,C,H,W) layout. Slow but needs no workspace.
__global__ __launch_bounds__(256) void attn_direct(
    const float* __restrict__ Q, const float* __restrict__ S, const float* __restrict__ R,
    const int* __restrict__ Pos, float* __restrict__ outBuf, float* __restrict__ outM)
{
    __shared__ float q_s[P_TILE][132];
    __shared__ float attn_s[P_TILE][17];
    __shared__ int   idx_s[P_TILE][K];
    __shared__ float out_s[P_TILE][132];

    const int tid = threadIdx.x;
    const int b   = blockIdx.x / BLOCKS_PER_BATCH;
    const int p0  = (blockIdx.x % BLOCKS_PER_BATCH) * P_TILE;

    for (int i = tid; i < P_TILE * C; i += 256) {
        int c = i >> 4, pl0 = i & 15;
        q_s[pl0][c] = Q[((size_t)(b * C + c)) * hw + p0 + pl0];
    }
    const int pl = tid >> 4;
    const int kk = tid & 15;
    const int p  = p0 + pl;
    const int rr = Pos[(((size_t)(b * 2 + 0) * hw) + p) * K + kk];
    const int cc = Pos[(((size_t)(b * 2 + 1) * hw) + p) * K + kk];
    const int idx = rr * W_ + cc;
    idx_s[pl][kk] = idx;
    __syncthreads();

    float score = 0.f;
    {
        const float* srow = S + (size_t)b * C * HW + idx;
        for (int c = 0; c < C; ++c) score += q_s[pl][c] * srow[(size_t)c * HW];
    }
    float mx = score;
    #pragma unroll
    for (int off = 1; off < 16; off <<= 1) mx = fmaxf(mx, __shfl_xor(mx, off));
    float e = __expf(score - mx);
    float ssum = e;
    #pragma unroll
    for (int off = 1; off < 16; off <<= 1) ssum += __shfl_xor(ssum, off);
    const float attn = e / ssum;
    outM[((size_t)b * hw + p) * K + kk] = attn;
    attn_s[pl][kk] = attn;
    __syncthreads();

    {
        const int pl2 = tid >> 4;
        const int cg  = tid & 15;
        float acc[8];
        #pragma unroll
        for (int i = 0; i < 8; ++i) acc[i] = 0.f;
        for (int k2 = 0; k2 < K; ++k2) {
            const float a = attn_s[pl2][k2];
            const float* rw = R + (size_t)b * C * HW + idx_s[pl2][k2];
            #pragma unroll
            for (int i = 0; i < 8; ++i) acc[i] += a * rw[(size_t)(cg * 8 + i) * HW];
        }
        #pragma unroll
        for (int i = 0; i < 8; ++i) out_s[pl2][cg * 8 + i] = acc[i];
    }
    __syncthreads();
    for (int i = tid; i < P_TILE * C; i += 256) {
        int c = i >> 4, pl3 = i & 15;
        outBuf[((size_t)(b * C + c)) * hw + p0 + pl3] = out_s[pl3][c];
    }
}

extern "C" void kernel_launch(void* const* d_in, const int* in_sizes, int n_in,
                              void* d_out, int out_size, void* d_ws, size_t ws_size,
                              hipStream_t stream)
{
    (void)in_sizes; (void)n_in; (void)out_size;
    const float* Q  = (const float*)d_in[0];
    const float* S  = (const float*)d_in[1];
    const float* R  = (const float*)d_in[2];
    const int*  Pos = (const int*)d_in[3];
    float* outBuf = (float*)d_out;
    float* outM   = outBuf + (size_t)B * C * hw;   // buffer is B*Cv*h*w elements

    const size_t perBatchElems = (size_t)HW * C;                              // 8,388,608
    const size_t fullBytes     = 2 * (size_t)B * perBatchElems * sizeof(float); // 256 MiB
    const size_t perBatchBytes = 2 * perBatchElems * sizeof(float);           // 64 MiB

    dim3 tb(64, 4);
    if (ws_size >= fullBytes) {
        // transpose all batches (S and R fused) in one launch, then one big compute launch
        float* St = (float*)d_ws;
        float* Rt = St + (size_t)B * perBatchElems;
        dim3 tg(HW / 64, C / 64, 2 * B);
        transpose_f32_both<<<tg, tb, 0, stream>>>(S, R, St, Rt);
        attn_gather<<<dim3(B * BLOCKS_PER_BATCH), 256, 0, stream>>>(
            Q, Pos, St, Rt, outBuf, outM, 0);
    } else if (ws_size >= perBatchBytes) {
        // per-batch transpose + compute, workspace reused
        float* St = (float*)d_ws;
        float* Rt = St + perBatchElems;
        dim3 tg(HW / 64, C / 64, 1);
        for (int b = 0; b < B; ++b) {
            transpose_f32<<<tg, tb, 0, stream>>>(S + (size_t)b * C * HW, St, HW);
            transpose_f32<<<tg, tb, 0, stream>>>(R + (size_t)b * C * HW, Rt, HW);
            attn_gather<<<dim3(BLOCKS_PER_BATCH), 256, 0, stream>>>(
                Q, Pos, St, Rt, outBuf, outM, b);
        }
    } else {
        // no usable workspace: direct (uncoalesced) gather
        attn_direct<<<dim3(B * BLOCKS_PER_BATCH), 256, 0, stream>>>(
            Q, S, R, Pos, outBuf, outM);
    }
}

// Round 2
// 401.602 us; speedup vs baseline: 1.4243x; 1.4243x over previous
//
#include <hip/hip_runtime.h>

// Problem constants (fixed by reference setup_inputs)
constexpr int B  = 4;
constexpr int C  = 128;    // == Cv
constexpr int hw = 16384;  // h*w = 128*128
constexpr int W_ = 256;
constexpr int HW = 65536;  // H*W
constexpr int K  = 16;
constexpr int P_TILE = 16;                       // positions per block
constexpr int BLOCKS_PER_BATCH = hw / P_TILE;    // 1024

typedef __attribute__((ext_vector_type(8))) _Float16 half8;
typedef __attribute__((ext_vector_type(2))) _Float16 half2v;

// Transpose+convert: S,R fp32 (C,HW) -> interleaved fp16 KV (HW, 256) per batch.
// KV[n][c] = S[c][n] for c<128, = R[c-128][n] for c>=128.
// One gather row (K|V at same idx) is 512B contiguous -> single burst per gather.
__global__ __launch_bounds__(256) void transpose_kv_f16(
    const float* __restrict__ S, const float* __restrict__ R,
    _Float16* __restrict__ KV)
{
    __shared__ float tS[64][65];
    __shared__ float tR[64][65];
    const int z  = blockIdx.z;
    const int n0 = blockIdx.x * 64;
    const int c0 = blockIdx.y * 64;
    const int tx = threadIdx.x;   // 0..63
    const int ty = threadIdx.y;   // 0..3
    const int tid = ty * 64 + tx;
    const float* s = S + (size_t)z * C * HW;
    const float* r = R + (size_t)z * C * HW;
    #pragma unroll
    for (int i = 0; i < 16; ++i) {
        int cl = ty + i * 4;
        tS[cl][tx] = s[(size_t)(c0 + cl) * HW + n0 + tx];   // coalesced 256B
        tR[cl][tx] = r[(size_t)(c0 + cl) * HW + n0 + tx];   // coalesced 256B
    }
    __syncthreads();
    _Float16* d = KV + (size_t)z * HW * 256;
    // write: 32 lanes cover one 64-channel segment as half2 (256B/wave-instr)
    #pragma unroll
    for (int i = 0; i < 8; ++i) {
        const int nl = (tid >> 5) + i * 8;        // row within tile
        const int j  = tid & 31;                   // channel pair
        _Float16* drow = d + (size_t)(n0 + nl) * 256;
        half2v hs, hr;
        hs[0] = (_Float16)tS[2 * j][nl];  hs[1] = (_Float16)tS[2 * j + 1][nl];
        hr[0] = (_Float16)tR[2 * j][nl];  hr[1] = (_Float16)tR[2 * j + 1][nl];
        *reinterpret_cast<half2v*>(drow + c0 + 2 * j)       = hs;   // K half
        *reinterpret_cast<half2v*>(drow + 128 + c0 + 2 * j) = hr;   // V half
    }
}

// Fused single-pass gather attention from interleaved fp16 KV rows.
// Per 16-lane group (one position p): for each of 16 gather rows, the group
// loads the full 512B K|V record cooperatively (2x16B per lane), computes the
// score via butterfly reduce, and online-softmax-accumulates V (flash-style
// running m, l). V is never refetched; each random gather is one 512B burst.
__global__ __launch_bounds__(256) void attn_gather_kv(
    const float* __restrict__ Q, const int* __restrict__ Pos,
    const _Float16* __restrict__ KV,
    float* __restrict__ outBuf, float* __restrict__ outM, int b0)
{
    __shared__ float q_s[P_TILE][132];   // Q tile, fp32, padded
    __shared__ float out_s[P_TILE][132];

    const int tid = threadIdx.x;
    const int bb  = blockIdx.x / BLOCKS_PER_BATCH;   // batch within this launch
    const int b   = b0 + bb;                         // absolute batch
    const int p0  = (blockIdx.x % BLOCKS_PER_BATCH) * P_TILE;

    // ---- stage Q tile (coalesced) ----
    for (int i = tid; i < P_TILE * C; i += 256) {
        int c = i >> 4, pl0 = i & 15;
        q_s[pl0][c] = Q[((size_t)(b * C + c)) * hw + p0 + pl0];
    }
    const int pl = tid >> 4;   // position in tile (= 16-lane group id)
    const int cg = tid & 15;   // lane within group
    const int p  = p0 + pl;
    int myidx;
    {
        const int rr = Pos[(((size_t)(b * 2 + 0) * hw) + p) * K + cg];   // coalesced
        const int cc = Pos[(((size_t)(b * 2 + 1) * hw) + p) * K + cg];
        myidx = rr * W_ + cc;
    }
    __syncthreads();

    float qf[8];
    #pragma unroll
    for (int i = 0; i < 8; ++i) qf[i] = q_s[pl][cg * 8 + i];

    float m = -1e30f, l = 0.f, myscore = 0.f;
    float acc[8];
    #pragma unroll
    for (int i = 0; i < 8; ++i) acc[i] = 0.f;

    const half8* base = reinterpret_cast<const half8*>(KV) + (size_t)bb * HW * 32;

    #pragma unroll
    for (int kc = 0; kc < K; kc += 4) {          // 4-row chunks: 8 loads in flight
        half8 kreg[4], vreg[4];
        #pragma unroll
        for (int r = 0; r < 4; ++r) {
            const int ridx = __shfl(myidx, kc + r, 16);    // group-uniform row idx
            const half8* row = base + (size_t)ridx * 32;   // 512B record, 512B aligned
            kreg[r] = row[cg];        // K halfs [cg*8, cg*8+8)
            vreg[r] = row[16 + cg];   // V halfs [cg*8, cg*8+8)
        }
        #pragma unroll
        for (int r = 0; r < 4; ++r) {
            float part = 0.f;
            #pragma unroll
            for (int i = 0; i < 8; ++i) part += qf[i] * (float)kreg[r][i];
            #pragma unroll
            for (int off = 1; off < 16; off <<= 1) part += __shfl_xor(part, off);
            // 'part' = score of row kc+r, identical across the 16-lane group
            const float mn    = fmaxf(m, part);
            const float scale = __expf(m - mn);      // ==1 when max unchanged; 0 on first row
            const float e     = __expf(part - mn);
            l = l * scale + e;
            #pragma unroll
            for (int i = 0; i < 8; ++i) acc[i] = acc[i] * scale + e * (float)vreg[r][i];
            m = mn;
            if (cg == kc + r) myscore = part;
        }
    }

    const float inv_l = 1.0f / l;
    const float attn  = __expf(myscore - m) * inv_l;   // == e_k / sum_k e_k
    outM[((size_t)b * hw + p) * K + cg] = attn;        // coalesced
    #pragma unroll
    for (int i = 0; i < 8; ++i) out_s[pl][cg * 8 + i] = acc[i] * inv_l;
    __syncthreads();
    for (int i = tid; i < P_TILE * C; i += 256) {
        int c = i >> 4, pl3 = i & 15;
        outBuf[((size_t)(b * C + c)) * hw + p0 + pl3] = out_s[pl3][c];   // coalesced
    }
}

// Fallback: direct gather from original (B,C,H,W) layout. Slow but needs no workspace.
__global__ __launch_bounds__(256) void attn_direct(
    const float* __restrict__ Q, const float* __restrict__ S, const float* __restrict__ R,
    const int* __restrict__ Pos, float* __restrict__ outBuf, float* __restrict__ outM)
{
    __shared__ float q_s[P_TILE][132];
    __shared__ float attn_s[P_TILE][17];
    __shared__ int   idx_s[P_TILE][K];
    __shared__ float out_s[P_TILE][132];

    const int tid = threadIdx.x;
    const int b   = blockIdx.x / BLOCKS_PER_BATCH;
    const int p0  = (blockIdx.x % BLOCKS_PER_BATCH) * P_TILE;

    for (int i = tid; i < P_TILE * C; i += 256) {
        int c = i >> 4, pl0 = i & 15;
        q_s[pl0][c] = Q[((size_t)(b * C + c)) * hw + p0 + pl0];
    }
    const int pl = tid >> 4;
    const int kk = tid & 15;
    const int p  = p0 + pl;
    const int rr = Pos[(((size_t)(b * 2 + 0) * hw) + p) * K + kk];
    const int cc = Pos[(((size_t)(b * 2 + 1) * hw) + p) * K + kk];
    const int idx = rr * W_ + cc;
    idx_s[pl][kk] = idx;
    __syncthreads();

    float score = 0.f;
    {
        const float* srow = S + (size_t)b * C * HW + idx;
        for (int c = 0; c < C; ++c) score += q_s[pl][c] * srow[(size_t)c * HW];
    }
    float mx = score;
    #pragma unroll
    for (int off = 1; off < 16; off <<= 1) mx = fmaxf(mx, __shfl_xor(mx, off));
    float e = __expf(score - mx);
    float ssum = e;
    #pragma unroll
    for (int off = 1; off < 16; off <<= 1) ssum += __shfl_xor(ssum, off);
    const float attn = e / ssum;
    outM[((size_t)b * hw + p) * K + kk] = attn;
    attn_s[pl][kk] = attn;
    __syncthreads();

    {
        const int pl2 = tid >> 4;
        const int cg  = tid & 15;
        float acc[8];
        #pragma unroll
        for (int i = 0; i < 8; ++i) acc[i] = 0.f;
        for (int k2 = 0; k2 < K; ++k2) {
            const float a = attn_s[pl2][k2];
            const float* rw = R + (size_t)b * C * HW + idx_s[pl2][k2];
            #pragma unroll
            for (int i = 0; i < 8; ++i) acc[i] += a * rw[(size_t)(cg * 8 + i) * HW];
        }
        #pragma unroll
        for (int i = 0; i < 8; ++i) out_s[pl2][cg * 8 + i] = acc[i];
    }
    __syncthreads();
    for (int i = tid; i < P_TILE * C; i += 256) {
        int c = i >> 4, pl3 = i & 15;
        outBuf[((size_t)(b * C + c)) * hw + p0 + pl3] = out_s[pl3][c];
    }
}

extern "C" void kernel_launch(void* const* d_in, const int* in_sizes, int n_in,
                              void* d_out, int out_size, void* d_ws, size_t ws_size,
                              hipStream_t stream)
{
    (void)in_sizes; (void)n_in; (void)out_size;
    const float* Q  = (const float*)d_in[0];
    const float* S  = (const float*)d_in[1];
    const float* R  = (const float*)d_in[2];
    const int*  Pos = (const int*)d_in[3];
    float* outBuf = (float*)d_out;
    float* outM   = outBuf + (size_t)B * C * hw;   // buffer is B*Cv*h*w elements

    const size_t fullBytes     = (size_t)B * HW * 256 * sizeof(_Float16);  // 128 MiB
    const size_t perBatchBytes = (size_t)HW * 256 * sizeof(_Float16);      // 32 MiB

    dim3 tb(64, 4);
    if (ws_size >= fullBytes) {
        // convert+interleave all batches in one launch, then one fused compute launch
        _Float16* KVt = (_Float16*)d_ws;
        dim3 tg(HW / 64, C / 64, B);
        transpose_kv_f16<<<tg, tb, 0, stream>>>(S, R, KVt);
        attn_gather_kv<<<dim3(B * BLOCKS_PER_BATCH), 256, 0, stream>>>(
            Q, Pos, KVt, outBuf, outM, 0);
    } else if (ws_size >= perBatchBytes) {
        // per-batch convert + compute, workspace reused
        _Float16* KVt = (_Float16*)d_ws;
        dim3 tg(HW / 64, C / 64, 1);
        for (int b = 0; b < B; ++b) {
            transpose_kv_f16<<<tg, tb, 0, stream>>>(
                S + (size_t)b * C * HW, R + (size_t)b * C * HW, KVt);
            attn_gather_kv<<<dim3(BLOCKS_PER_BATCH), 256, 0, stream>>>(
                Q, Pos, KVt, outBuf, outM, b);
        }
    } else {
        // no usable workspace: direct (uncoalesced) fp32 gather
        attn_direct<<<dim3(B * BLOCKS_PER_BATCH), 256, 0, stream>>>(
            Q, S, R, Pos, outBuf, outM);
    }
}